// Round 14
// baseline (111.816 us; speedup 1.0000x reference)
//
#include <hip/hip_runtime.h>
#include <hip/hip_bf16.h>

// SparseLinear: out[8192,128] = sum over COO entries (r,c,v): out[r,:] += v * x[c,:]
// R14: R13 with CHK=4096/NG=512 and 512-thread chunksort blocks -> 32KB stage,
// 2 blocks/CU (cross-block phase overlap; chunksort was ~6x over its BW floor at
// 1 block/CU). bucketspmm: only mechanical run-table changes (512 runs, 9-step
// search); sort + gather loops byte-identical to R13 (incl. unmasked-high unpack).

#define M_ROWS 8192
#define B_COLS 128
#define NG   512      // chunks
#define CHK  4096     // entries per chunk (nnz / NG)
#define NBK  512      // coarse buckets (row >> 4), 16 rows each
#define CAP  5120     // LDS-staged entries per bucket; mean 4096, sigma 64 -> +16 sigma

__device__ inline unsigned int f2bf(float f) {
    unsigned int u = __float_as_uint(f);
    return ((u + 0x7fffu + ((u >> 16) & 1u)) >> 16) & 0xFFFFu;
}

// ---------- K1: per-chunk LDS bucket-sort + x->bf16 slice conversion -------
// 512 threads, 32KB stage -> 2 blocks/CU. Block g converts its 2048-float x
// slice, sorts its 4096-entry chunk by bucket in LDS, writes chunk-contiguous
// + binStartT[b][g].
__global__ void __launch_bounds__(512) chunksort_kernel(const int* __restrict__ rows,
                                                        const int* __restrict__ cols,
                                                        const float* __restrict__ vals,
                                                        int nnz,
                                                        const float* __restrict__ x,
                                                        uint2* __restrict__ xb2,
                                                        int* __restrict__ binStartT,
                                                        int2* __restrict__ pairs) {
    __shared__ int2 stage[CHK];                    // 32 KB
    __shared__ int hist[NBK];                      // counts -> cursors
    __shared__ int binStart[NBK];
    __shared__ int gbase[64];
    int t = threadIdx.x, g = blockIdx.x;
    int s = g * CHK, e = min(s + CHK, nnz);
    int cnt = e - s;

    // ---- fused convx: 2048 floats -> 512 uint2 per block ----
    {
        const float4* px = (const float4*)x + (size_t)g * 512 + t;
        float4 a = px[0];
        uint2 o;
        o.x = f2bf(a.x) | (f2bf(a.y) << 16);
        o.y = f2bf(a.z) | (f2bf(a.w) << 16);
        xb2[(size_t)g * 512 + t] = o;
    }

    int   rr[CHK / 512];
    int   cc[CHK / 512];
    float vv[CHK / 512];
    for (int i = t; i < NBK; i += 512) hist[i] = 0;
    __syncthreads();
#pragma unroll
    for (int k = 0; k < CHK / 512; ++k) {
        int i = s + t + k * 512;
        if (i < e) {
            rr[k] = rows[i];
            cc[k] = cols[i];
            vv[k] = vals[i];
            atomicAdd(&hist[rr[k] >> 4], 1);
        } else rr[k] = -1;
    }
    __syncthreads();
    if (t < 64) {
        int gs = 0;
#pragma unroll
        for (int k = 0; k < 8; ++k) gs += hist[t * 8 + k];
        gbase[t] = gs;
    }
    __syncthreads();
    if (t == 0) {
        int acc = 0;
        for (int i = 0; i < 64; ++i) { int c = gbase[i]; gbase[i] = acc; acc += c; }
    }
    __syncthreads();
    {
        int off = gbase[t >> 3];
        for (int k = (t & ~7); k < t; ++k) off += hist[k];
        binStart[t] = off;
        binStartT[(size_t)t * NG + g] = off;       // publish local bin start
    }
    __syncthreads();
    hist[t] = binStart[t];                         // hist becomes cursor
    __syncthreads();
#pragma unroll
    for (int k = 0; k < CHK / 512; ++k) {
        if (rr[k] >= 0) {
            int pos = atomicAdd(&hist[rr[k] >> 4], 1);
            stage[pos] = make_int2((rr[k] << 13) | cc[k], __float_as_int(vv[k]));
        }
    }
    __syncthreads();
    // chunk-contiguous coalesced writeout (sorted by bucket within the chunk)
#pragma unroll
    for (int k = 0; k < CHK / 512; ++k) {
        int i = t + k * 512;
        if (i < cnt) pairs[s + i] = stage[i];
    }
}

// ---------- K2: per-bucket run-gather + LDS sort + spmm --------------------
// 1024 threads = 16 waves = 16 rows. 512-run table (9-step binary search);
// sort + gather verbatim R13 (quarter-wave uint4 gather, unmasked-high unpack).
__global__ void __launch_bounds__(1024) bucketspmm_kernel(const int2* __restrict__ pairs,
                                                          const int* __restrict__ binStartT,
                                                          int nnz,
                                                          const unsigned short* __restrict__ xb,
                                                          float* __restrict__ out) {
    __shared__ int2 sorted[CAP];                   // 40 KB
    __shared__ int runPrefix[NG + 1];              // exclusive entry-prefix per run
    __shared__ int runAddr[NG];                    // global pairs index of run start
    __shared__ int gb32[32];
    __shared__ int h16w[16 * 16];                  // [wave][bin]
    __shared__ int h16tot[16];
    __shared__ int rs[17];
    int t = threadIdx.x;
    int bkt = blockIdx.x;
    int wave = t >> 6, lane = t & 63;

    // ---- run table: length + address per chunk ----
    if (t < NG) {
        int g = t;
        int st = binStartT[(size_t)bkt * NG + g];
        int en;
        if (bkt == NBK - 1) en = min(CHK, nnz - g * CHK);
        else                en = binStartT[(size_t)(bkt + 1) * NG + g];
        runAddr[g] = g * CHK + st;
        runPrefix[g] = en - st;                    // temporarily: run length
    }
    if (t < 256) h16w[t] = 0;
    __syncthreads();
    if (t < 32) {
        int gs = 0;
#pragma unroll
        for (int k = 0; k < 16; ++k) gs += runPrefix[t * 16 + k];
        gb32[t] = gs;
    }
    __syncthreads();
    if (t == 0) {
        int acc = 0;
        for (int i = 0; i < 32; ++i) { int c = gb32[i]; gb32[i] = acc; acc += c; }
    }
    __syncthreads();
    int myoff = 0, mylen = 0;
    if (t < NG) {
        mylen = runPrefix[t];
        myoff = gb32[t >> 4];
        for (int k = (t & ~15); k < t; ++k) myoff += runPrefix[k];
    }
    __syncthreads();
    if (t < NG) runPrefix[t] = myoff;              // now: exclusive prefix
    if (t == NG - 1) runPrefix[NG] = myoff + mylen;
    __syncthreads();

    int n = runPrefix[NG];
    int nc = min(n, CAP);

    // ---- staged load via run binary search + per-wave 16-bin hist ----
    int2 buf[5];                                   // CAP = 5 * 1024
#pragma unroll
    for (int k = 0; k < 5; ++k) {
        int i = t + 1024 * k;
        if (i < nc) {
            int lo = 0, hi = NG - 1;
#pragma unroll
            for (int st9 = 0; st9 < 9; ++st9) {
                int mid = (lo + hi + 1) >> 1;
                if (runPrefix[mid] <= i) lo = mid; else hi = mid - 1;
            }
            int2 en = pairs[runAddr[lo] + (i - runPrefix[lo])];
            buf[k] = en;
            atomicAdd(&h16w[wave * 16 + ((en.x >> 13) & 15)], 1);
        }
    }
    __syncthreads();
    if (t < 16) {                                  // bin = t: exclusive over waves
        int acc = 0;
#pragma unroll
        for (int w = 0; w < 16; ++w) {
            int c = h16w[w * 16 + t];
            h16w[w * 16 + t] = acc;
            acc += c;
        }
        h16tot[t] = acc;
    }
    __syncthreads();
    if (t == 0) {
        int acc = 0;
#pragma unroll
        for (int j = 0; j < 16; ++j) { rs[j] = acc; acc += h16tot[j]; }
        rs[16] = acc;
    }
    __syncthreads();
    if (t < 256) {                                 // per-wave cursor = rs[bin] + wave prefix
        int w = t >> 4, b = t & 15;
        h16w[t] = rs[b] + h16w[w * 16 + b];
    }
    __syncthreads();
#pragma unroll
    for (int k = 0; k < 5; ++k) {
        int i = t + 1024 * k;
        if (i < nc) {
            int2 en = buf[k];
            int pos = atomicAdd(&h16w[wave * 16 + ((en.x >> 13) & 15)], 1);
            sorted[pos] = make_int2(en.x & 8191, en.y);
        }
    }
    __syncthreads();

    // ---- spmm: wave `wave` computes row (bkt*16 + wave) ----
    int g = lane >> 4, l16 = lane & 15;
    const unsigned short* xbl = xb + l16 * 8;
    int b0 = rs[wave], e0 = rs[wave + 1];
    float acc[8];
#pragma unroll
    for (int k = 0; k < 8; ++k) acc[k] = 0.f;

    for (int i = b0; i < e0; i += 16) {
        int i0 = i + g, i1 = i0 + 4, i2 = i0 + 8, i3 = i0 + 12;
        int2 ea = (i0 < e0) ? sorted[i0] : make_int2(0, 0);
        int2 eb = (i1 < e0) ? sorted[i1] : make_int2(0, 0);
        int2 ec = (i2 < e0) ? sorted[i2] : make_int2(0, 0);
        int2 ed = (i3 < e0) ? sorted[i3] : make_int2(0, 0);
        float va = (i0 < e0) ? __int_as_float(ea.y) : 0.f;
        float vb = (i1 < e0) ? __int_as_float(eb.y) : 0.f;
        float vc = (i2 < e0) ? __int_as_float(ec.y) : 0.f;
        float vd = (i3 < e0) ? __int_as_float(ed.y) : 0.f;
        const uint4 qa = *(const uint4*)(xbl + (size_t)ea.x * B_COLS);
        const uint4 qb = *(const uint4*)(xbl + (size_t)eb.x * B_COLS);
        const uint4 qc = *(const uint4*)(xbl + (size_t)ec.x * B_COLS);
        const uint4 qd = *(const uint4*)(xbl + (size_t)ed.x * B_COLS);
        // low half: exact (shift); high half: UNMASKED (rel err < 2^-8)
#pragma unroll
        for (int k = 0; k < 4; ++k) {
            unsigned int w = (&qa.x)[k];
            acc[2 * k]     = fmaf(va, __uint_as_float(w << 16), acc[2 * k]);
            acc[2 * k + 1] = fmaf(va, __uint_as_float(w), acc[2 * k + 1]);
        }
#pragma unroll
        for (int k = 0; k < 4; ++k) {
            unsigned int w = (&qb.x)[k];
            acc[2 * k]     = fmaf(vb, __uint_as_float(w << 16), acc[2 * k]);
            acc[2 * k + 1] = fmaf(vb, __uint_as_float(w), acc[2 * k + 1]);
        }
#pragma unroll
        for (int k = 0; k < 4; ++k) {
            unsigned int w = (&qc.x)[k];
            acc[2 * k]     = fmaf(vc, __uint_as_float(w << 16), acc[2 * k]);
            acc[2 * k + 1] = fmaf(vc, __uint_as_float(w), acc[2 * k + 1]);
        }
#pragma unroll
        for (int k = 0; k < 4; ++k) {
            unsigned int w = (&qd.x)[k];
            acc[2 * k]     = fmaf(vd, __uint_as_float(w << 16), acc[2 * k]);
            acc[2 * k + 1] = fmaf(vd, __uint_as_float(w), acc[2 * k + 1]);
        }
    }
    // overflow tail (n > CAP): correct but never taken for this data
    for (int i = CAP; i < n; ++i) {
        int lo = 0, hi = NG - 1;
        for (int st9 = 0; st9 < 9; ++st9) {
            int mid = (lo + hi + 1) >> 1;
            if (runPrefix[mid] <= i) lo = mid; else hi = mid - 1;
        }
        int2 en = pairs[runAddr[lo] + (i - runPrefix[lo])];
        if (((en.x >> 13) & 15) == wave) {
            float v = (g == 0) ? __int_as_float(en.y) : 0.f;
            const uint4 q = *(const uint4*)(xbl + (size_t)(en.x & 8191) * B_COLS);
#pragma unroll
            for (int k = 0; k < 4; ++k) {
                unsigned int w = (&q.x)[k];
                acc[2 * k]     = fmaf(v, __uint_as_float(w << 16), acc[2 * k]);
                acc[2 * k + 1] = fmaf(v, __uint_as_float(w), acc[2 * k + 1]);
            }
        }
    }
#pragma unroll
    for (int k = 0; k < 8; ++k) {
        acc[k] += __shfl_xor(acc[k], 16, 64);
        acc[k] += __shfl_xor(acc[k], 32, 64);
    }
    if (lane < 16) {
        float* op = out + ((size_t)(bkt * 16 + wave)) * B_COLS + l16 * 8;
        *(float4*)op       = make_float4(acc[0], acc[1], acc[2], acc[3]);
        *((float4*)op + 1) = make_float4(acc[4], acc[5], acc[6], acc[7]);
    }
}

// ---------- Fallback if workspace too small / unexpected shape -------------
__global__ void atomic_spmm_kernel(const int* __restrict__ rows, const int* __restrict__ cols,
                                   const float* __restrict__ vals, int nnz,
                                   const float* __restrict__ x, float* __restrict__ out) {
    long long tid = (long long)blockIdx.x * blockDim.x + threadIdx.x;
    int e = (int)(tid >> 5);
    int g = (int)(tid & 31);
    if (e < nnz) {
        int r = rows[e], c = cols[e];
        float v = vals[e];
        const float4 xv = *(const float4*)(x + (size_t)c * B_COLS + g * 4);
        float* o = out + (size_t)r * B_COLS + g * 4;
        atomicAdd(o + 0, v * xv.x);
        atomicAdd(o + 1, v * xv.y);
        atomicAdd(o + 2, v * xv.z);
        atomicAdd(o + 3, v * xv.w);
    }
}

extern "C" void kernel_launch(void* const* d_in, const int* in_sizes, int n_in,
                              void* d_out, int out_size, void* d_ws, size_t ws_size,
                              hipStream_t stream) {
    const int*   ids  = (const int*)d_in[0];
    const int    nnz  = in_sizes[0] / 2;
    const int*   rows = ids;
    const int*   cols = ids + nnz;
    const float* vals = (const float*)d_in[1];
    const float* x    = (const float*)d_in[2];
    float*       out  = (float*)d_out;

    // ws (ints): binStartT[NBK*NG] | pad-to-16B | xbf[1M bf16 = 512K ints] | pairs[nnz] int2
    size_t o_binStartT = 0;
    size_t o_xbf       = (o_binStartT + (size_t)NBK * NG + 3) & ~(size_t)3;   // 16B align
    size_t o_pairs     = o_xbf + (size_t)M_ROWS * B_COLS / 2;
    size_t need_bytes  = (o_pairs + (size_t)nnz * 2) * 4;
    int ngrid = (nnz + CHK - 1) / CHK;             // = NG for this data

    if (ws_size >= need_bytes && ngrid == NG) {
        int*            binStartT = (int*)d_ws + o_binStartT;
        unsigned short* xbf       = (unsigned short*)((int*)d_ws + o_xbf);
        int2*           pairs     = (int2*)((int*)d_ws + o_pairs);

        chunksort_kernel<<<NG, 512, 0, stream>>>(rows, cols, vals, nnz,
                                                 x, (uint2*)xbf, binStartT, pairs);
        bucketspmm_kernel<<<NBK, 1024, 0, stream>>>(pairs, binStartT, nnz, xbf, out);
    } else {
        hipMemsetAsync(d_out, 0, (size_t)out_size * sizeof(float), stream);
        long long total = (long long)nnz * 32;
        atomic_spmm_kernel<<<(unsigned)((total + 255) / 256), 256, 0, stream>>>(rows, cols, vals, nnz, x, out);
    }
}

// Round 15
// 109.983 us; speedup vs baseline: 1.0167x; 1.0167x over previous
//
#include <hip/hip_runtime.h>
#include <hip/hip_bf16.h>

// SparseLinear: out[8192,128] = sum over COO entries (r,c,v): out[r,:] += v * x[c,:]
// R15: exact R13 pipeline (best: 110.7us) with ONE change: bucketspmm's FMA loop
// uses v_pk_fma_f32 (packed fp32) via <2 x float> __builtin_elementwise_fma with
// the unmasked-high bf16 pair {w<<16, w} -> 4 shifts + 4 pk_fma per entry
// instead of 4 shifts + 8 scalar FMAs (~33% fewer hot-loop VALU ops; R12 profile
// showed bucketspmm VALU-issue-bound at 60% VALUBusy).

#define M_ROWS 8192
#define B_COLS 128
#define NG   256      // chunks
#define CHK  8192     // entries per chunk (nnz / NG)
#define NBK  512      // coarse buckets (row >> 4), 16 rows each
#define CAP  5120     // LDS-staged entries per bucket; mean 4096, sigma 64 -> +16 sigma

typedef float v2f __attribute__((ext_vector_type(2)));

__device__ inline unsigned int f2bf(float f) {
    unsigned int u = __float_as_uint(f);
    return ((u + 0x7fffu + ((u >> 16) & 1u)) >> 16) & 0xFFFFu;
}

// ---------- K1: per-chunk LDS bucket-sort + x->bf16 slice conversion -------
// Block g converts x floats [g*4096, (g+1)*4096) to bf16 (xbf), then sorts its
// entry chunk by bucket in LDS and writes chunk-contiguous + binStartT.
__global__ void __launch_bounds__(1024) chunksort_kernel(const int* __restrict__ rows,
                                                         const int* __restrict__ cols,
                                                         const float* __restrict__ vals,
                                                         int nnz,
                                                         const float* __restrict__ x,
                                                         uint4* __restrict__ xb,
                                                         int* __restrict__ binStartT,
                                                         int2* __restrict__ pairs) {
    __shared__ int2 stage[CHK];                    // 64 KB
    __shared__ int hist[NBK];                      // counts -> cursors
    __shared__ int binStart[NBK];
    __shared__ int gbase[64];
    int t = threadIdx.x, g = blockIdx.x;
    int s = g * CHK, e = min(s + CHK, nnz);
    int cnt = e - s;

    // ---- fused convx: 4096 floats -> 512 uint4 per block (t < 512) ----
    if (t < 512) {
        const float4* px = (const float4*)x + (size_t)g * 1024 + t * 2;
        float4 a = px[0], b = px[1];
        uint4 o;
        o.x = f2bf(a.x) | (f2bf(a.y) << 16);
        o.y = f2bf(a.z) | (f2bf(a.w) << 16);
        o.z = f2bf(b.x) | (f2bf(b.y) << 16);
        o.w = f2bf(b.z) | (f2bf(b.w) << 16);
        xb[(size_t)g * 512 + t] = o;
    }

    int   rr[CHK / 1024];
    int   cc[CHK / 1024];
    float vv[CHK / 1024];
    for (int i = t; i < NBK; i += 1024) hist[i] = 0;
    __syncthreads();
#pragma unroll
    for (int k = 0; k < CHK / 1024; ++k) {
        int i = s + t + k * 1024;
        if (i < e) {
            rr[k] = rows[i];
            cc[k] = cols[i];
            vv[k] = vals[i];
            atomicAdd(&hist[rr[k] >> 4], 1);
        } else rr[k] = -1;
    }
    __syncthreads();
    if (t < 64) {
        int gs = 0;
#pragma unroll
        for (int k = 0; k < 8; ++k) gs += hist[t * 8 + k];
        gbase[t] = gs;
    }
    __syncthreads();
    if (t == 0) {
        int acc = 0;
        for (int i = 0; i < 64; ++i) { int c = gbase[i]; gbase[i] = acc; acc += c; }
    }
    __syncthreads();
    if (t < NBK) {
        int off = gbase[t >> 3];
        for (int k = (t & ~7); k < t; ++k) off += hist[k];
        binStart[t] = off;
        binStartT[(size_t)t * NG + g] = off;       // publish local bin start
    }
    __syncthreads();
    if (t < NBK) hist[t] = binStart[t];            // hist becomes cursor
    __syncthreads();
#pragma unroll
    for (int k = 0; k < CHK / 1024; ++k) {
        if (rr[k] >= 0) {
            int pos = atomicAdd(&hist[rr[k] >> 4], 1);
            stage[pos] = make_int2((rr[k] << 13) | cc[k], __float_as_int(vv[k]));
        }
    }
    __syncthreads();
    // chunk-contiguous coalesced writeout (sorted by bucket within the chunk)
#pragma unroll
    for (int k = 0; k < CHK / 1024; ++k) {
        int i = t + k * 1024;
        if (i < cnt) pairs[s + i] = stage[i];
    }
}

// ---------- K2: per-bucket run-gather + LDS sort + spmm --------------------
// 1024 threads = 16 waves = 16 rows. Run table + sort verbatim R13. Gather:
// quarter-wave per entry (16 lanes x uint4), 16 entries/iter; packed FMA with
// unmasked-high bf16 pairs.
__global__ void __launch_bounds__(1024) bucketspmm_kernel(const int2* __restrict__ pairs,
                                                          const int* __restrict__ binStartT,
                                                          int nnz,
                                                          const unsigned short* __restrict__ xb,
                                                          float* __restrict__ out) {
    __shared__ int2 sorted[CAP];                   // 40 KB
    __shared__ int runPrefix[NG + 1];              // exclusive entry-prefix per run
    __shared__ int runAddr[NG];                    // global pairs index of run start
    __shared__ int gb16[16];
    __shared__ int h16w[16 * 16];                  // [wave][bin]
    __shared__ int h16tot[16];
    __shared__ int rs[17];
    int t = threadIdx.x;
    int bkt = blockIdx.x;
    int wave = t >> 6, lane = t & 63;

    // ---- run table: length + address per chunk ----
    if (t < NG) {
        int g = t;
        int st = binStartT[(size_t)bkt * NG + g];
        int en;
        if (bkt == NBK - 1) en = min(CHK, nnz - g * CHK);
        else                en = binStartT[(size_t)(bkt + 1) * NG + g];
        runAddr[g] = g * CHK + st;
        runPrefix[g] = en - st;                    // temporarily: run length
    }
    if (t < 256) h16w[t] = 0;
    __syncthreads();
    if (t < 16) {
        int gs = 0;
#pragma unroll
        for (int k = 0; k < 16; ++k) gs += runPrefix[t * 16 + k];
        gb16[t] = gs;
    }
    __syncthreads();
    if (t == 0) {
        int acc = 0;
        for (int i = 0; i < 16; ++i) { int c = gb16[i]; gb16[i] = acc; acc += c; }
    }
    __syncthreads();
    int myoff = 0, mylen = 0;
    if (t < NG) {
        mylen = runPrefix[t];
        myoff = gb16[t >> 4];
        for (int k = (t & ~15); k < t; ++k) myoff += runPrefix[k];
    }
    __syncthreads();
    if (t < NG) runPrefix[t] = myoff;              // now: exclusive prefix
    if (t == NG - 1) runPrefix[NG] = myoff + mylen;
    __syncthreads();

    int n = runPrefix[NG];
    int nc = min(n, CAP);

    // ---- staged load via run binary search + per-wave 16-bin hist ----
    int2 buf[5];                                   // CAP = 5 * 1024
#pragma unroll
    for (int k = 0; k < 5; ++k) {
        int i = t + 1024 * k;
        if (i < nc) {
            int lo = 0, hi = NG - 1;
#pragma unroll
            for (int st8 = 0; st8 < 8; ++st8) {
                int mid = (lo + hi + 1) >> 1;
                if (runPrefix[mid] <= i) lo = mid; else hi = mid - 1;
            }
            int2 en = pairs[runAddr[lo] + (i - runPrefix[lo])];
            buf[k] = en;
            atomicAdd(&h16w[wave * 16 + ((en.x >> 13) & 15)], 1);
        }
    }
    __syncthreads();
    if (t < 16) {                                  // bin = t: exclusive over waves
        int acc = 0;
#pragma unroll
        for (int w = 0; w < 16; ++w) {
            int c = h16w[w * 16 + t];
            h16w[w * 16 + t] = acc;
            acc += c;
        }
        h16tot[t] = acc;
    }
    __syncthreads();
    if (t == 0) {
        int acc = 0;
#pragma unroll
        for (int j = 0; j < 16; ++j) { rs[j] = acc; acc += h16tot[j]; }
        rs[16] = acc;
    }
    __syncthreads();
    if (t < 256) {                                 // per-wave cursor = rs[bin] + wave prefix
        int w = t >> 4, b = t & 15;
        h16w[t] = rs[b] + h16w[w * 16 + b];
    }
    __syncthreads();
#pragma unroll
    for (int k = 0; k < 5; ++k) {
        int i = t + 1024 * k;
        if (i < nc) {
            int2 en = buf[k];
            int pos = atomicAdd(&h16w[wave * 16 + ((en.x >> 13) & 15)], 1);
            sorted[pos] = make_int2(en.x & 8191, en.y);
        }
    }
    __syncthreads();

    // ---- spmm: wave `wave` computes row (bkt*16 + wave) ----
    int g = lane >> 4, l16 = lane & 15;
    const unsigned short* xbl = xb + l16 * 8;
    int b0 = rs[wave], e0 = rs[wave + 1];
    v2f acc2[4];
#pragma unroll
    for (int k = 0; k < 4; ++k) acc2[k] = (v2f){0.f, 0.f};

    for (int i = b0; i < e0; i += 16) {
        int i0 = i + g, i1 = i0 + 4, i2 = i0 + 8, i3 = i0 + 12;
        int2 ea = (i0 < e0) ? sorted[i0] : make_int2(0, 0);
        int2 eb = (i1 < e0) ? sorted[i1] : make_int2(0, 0);
        int2 ec = (i2 < e0) ? sorted[i2] : make_int2(0, 0);
        int2 ed = (i3 < e0) ? sorted[i3] : make_int2(0, 0);
        float va = (i0 < e0) ? __int_as_float(ea.y) : 0.f;
        float vb = (i1 < e0) ? __int_as_float(eb.y) : 0.f;
        float vc = (i2 < e0) ? __int_as_float(ec.y) : 0.f;
        float vd = (i3 < e0) ? __int_as_float(ed.y) : 0.f;
        const uint4 qa = *(const uint4*)(xbl + (size_t)ea.x * B_COLS);
        const uint4 qb = *(const uint4*)(xbl + (size_t)eb.x * B_COLS);
        const uint4 qc = *(const uint4*)(xbl + (size_t)ec.x * B_COLS);
        const uint4 qd = *(const uint4*)(xbl + (size_t)ed.x * B_COLS);
        // packed FMA: pair = {low bf16 (exact shift), high bf16 (UNMASKED, rel err < 2^-8)}
        v2f pva = (v2f){va, va}, pvb = (v2f){vb, vb};
        v2f pvc = (v2f){vc, vc}, pvd = (v2f){vd, vd};
#pragma unroll
        for (int k = 0; k < 4; ++k) {
            unsigned int w = (&qa.x)[k];
            v2f xv = (v2f){__uint_as_float(w << 16), __uint_as_float(w)};
            acc2[k] = __builtin_elementwise_fma(pva, xv, acc2[k]);
        }
#pragma unroll
        for (int k = 0; k < 4; ++k) {
            unsigned int w = (&qb.x)[k];
            v2f xv = (v2f){__uint_as_float(w << 16), __uint_as_float(w)};
            acc2[k] = __builtin_elementwise_fma(pvb, xv, acc2[k]);
        }
#pragma unroll
        for (int k = 0; k < 4; ++k) {
            unsigned int w = (&qc.x)[k];
            v2f xv = (v2f){__uint_as_float(w << 16), __uint_as_float(w)};
            acc2[k] = __builtin_elementwise_fma(pvc, xv, acc2[k]);
        }
#pragma unroll
        for (int k = 0; k < 4; ++k) {
            unsigned int w = (&qd.x)[k];
            v2f xv = (v2f){__uint_as_float(w << 16), __uint_as_float(w)};
            acc2[k] = __builtin_elementwise_fma(pvd, xv, acc2[k]);
        }
    }
    // overflow tail (n > CAP): correct but never taken for this data
    for (int i = CAP; i < n; ++i) {
        int lo = 0, hi = NG - 1;
        for (int st8 = 0; st8 < 8; ++st8) {
            int mid = (lo + hi + 1) >> 1;
            if (runPrefix[mid] <= i) lo = mid; else hi = mid - 1;
        }
        int2 en = pairs[runAddr[lo] + (i - runPrefix[lo])];
        if (((en.x >> 13) & 15) == wave) {
            float v = (g == 0) ? __int_as_float(en.y) : 0.f;
            v2f pv = (v2f){v, v};
            const uint4 q = *(const uint4*)(xbl + (size_t)(en.x & 8191) * B_COLS);
#pragma unroll
            for (int k = 0; k < 4; ++k) {
                unsigned int w = (&q.x)[k];
                v2f xv = (v2f){__uint_as_float(w << 16), __uint_as_float(w)};
                acc2[k] = __builtin_elementwise_fma(pv, xv, acc2[k]);
            }
        }
    }
    float acc[8];
#pragma unroll
    for (int k = 0; k < 4; ++k) { acc[2 * k] = acc2[k].x; acc[2 * k + 1] = acc2[k].y; }
#pragma unroll
    for (int k = 0; k < 8; ++k) {
        acc[k] += __shfl_xor(acc[k], 16, 64);
        acc[k] += __shfl_xor(acc[k], 32, 64);
    }
    if (lane < 16) {
        float* op = out + ((size_t)(bkt * 16 + wave)) * B_COLS + l16 * 8;
        *(float4*)op       = make_float4(acc[0], acc[1], acc[2], acc[3]);
        *((float4*)op + 1) = make_float4(acc[4], acc[5], acc[6], acc[7]);
    }
}

// ---------- Fallback if workspace too small / unexpected shape -------------
__global__ void atomic_spmm_kernel(const int* __restrict__ rows, const int* __restrict__ cols,
                                   const float* __restrict__ vals, int nnz,
                                   const float* __restrict__ x, float* __restrict__ out) {
    long long tid = (long long)blockIdx.x * blockDim.x + threadIdx.x;
    int e = (int)(tid >> 5);
    int g = (int)(tid & 31);
    if (e < nnz) {
        int r = rows[e], c = cols[e];
        float v = vals[e];
        const float4 xv = *(const float4*)(x + (size_t)c * B_COLS + g * 4);
        float* o = out + (size_t)r * B_COLS + g * 4;
        atomicAdd(o + 0, v * xv.x);
        atomicAdd(o + 1, v * xv.y);
        atomicAdd(o + 2, v * xv.z);
        atomicAdd(o + 3, v * xv.w);
    }
}

extern "C" void kernel_launch(void* const* d_in, const int* in_sizes, int n_in,
                              void* d_out, int out_size, void* d_ws, size_t ws_size,
                              hipStream_t stream) {
    const int*   ids  = (const int*)d_in[0];
    const int    nnz  = in_sizes[0] / 2;
    const int*   rows = ids;
    const int*   cols = ids + nnz;
    const float* vals = (const float*)d_in[1];
    const float* x    = (const float*)d_in[2];
    float*       out  = (float*)d_out;

    // ws (ints): binStartT[NBK*NG] | pad-to-16B | xbf[1M bf16 = 512K ints] | pairs[nnz] int2
    size_t o_binStartT = 0;
    size_t o_xbf       = (o_binStartT + (size_t)NBK * NG + 3) & ~(size_t)3;   // 16B align
    size_t o_pairs     = o_xbf + (size_t)M_ROWS * B_COLS / 2;
    size_t need_bytes  = (o_pairs + (size_t)nnz * 2) * 4;
    int ngrid = (nnz + CHK - 1) / CHK;             // = NG for this data

    if (ws_size >= need_bytes && ngrid == NG) {
        int*            binStartT = (int*)d_ws + o_binStartT;
        unsigned short* xbf       = (unsigned short*)((int*)d_ws + o_xbf);
        int2*           pairs     = (int2*)((int*)d_ws + o_pairs);

        chunksort_kernel<<<NG, 1024, 0, stream>>>(rows, cols, vals, nnz,
                                                  x, (uint4*)xbf, binStartT, pairs);
        bucketspmm_kernel<<<NBK, 1024, 0, stream>>>(pairs, binStartT, nnz, xbf, out);
    } else {
        hipMemsetAsync(d_out, 0, (size_t)out_size * sizeof(float), stream);
        long long total = (long long)nnz * 32;
        atomic_spmm_kernel<<<(unsigned)((total + 255) / 256), 256, 0, stream>>>(rows, cols, vals, nnz, x, out);
    }
}

// Round 16
// 109.868 us; speedup vs baseline: 1.0177x; 1.0010x over previous
//
#include <hip/hip_runtime.h>
#include <hip/hip_bf16.h>

// SparseLinear: out[8192,128] = sum over COO entries (r,c,v): out[r,:] += v * x[c,:]
// R16: R15 pipeline (best: 110.0us) with ONE change: chunksort uses 4-way
// replicated LDS hist/cursors (replica = wave&3) -> 4x less same-address
// LDS-atomic serialization in the hist and scatter phases. bucketspmm verbatim
// R15 (packed FMA + unmasked-high unpack).

#define M_ROWS 8192
#define B_COLS 128
#define NG   256      // chunks
#define CHK  8192     // entries per chunk (nnz / NG)
#define NBK  512      // coarse buckets (row >> 4), 16 rows each
#define CAP  5120     // LDS-staged entries per bucket; mean 4096, sigma 64 -> +16 sigma

typedef float v2f __attribute__((ext_vector_type(2)));

__device__ inline unsigned int f2bf(float f) {
    unsigned int u = __float_as_uint(f);
    return ((u + 0x7fffu + ((u >> 16) & 1u)) >> 16) & 0xFFFFu;
}

// ---------- K1: per-chunk LDS bucket-sort + x->bf16 slice conversion -------
// Block g converts x floats [g*4096, (g+1)*4096) to bf16 (xbf), then sorts its
// entry chunk by bucket in LDS (4-way replicated hist/cursors) and writes
// chunk-contiguous + binStartT.
__global__ void __launch_bounds__(1024) chunksort_kernel(const int* __restrict__ rows,
                                                         const int* __restrict__ cols,
                                                         const float* __restrict__ vals,
                                                         int nnz,
                                                         const float* __restrict__ x,
                                                         uint4* __restrict__ xb,
                                                         int* __restrict__ binStartT,
                                                         int2* __restrict__ pairs) {
    __shared__ int2 stage[CHK];                    // 64 KB
    __shared__ int hist4[4][NBK];                  // replicated counts -> cursors (8 KB)
    __shared__ int binStart[NBK];
    __shared__ int gbase[64];
    int t = threadIdx.x, g = blockIdx.x;
    int s = g * CHK, e = min(s + CHK, nnz);
    int cnt = e - s;
    int rep = (t >> 6) & 3;                        // wave & 3

    // ---- fused convx: 4096 floats -> 512 uint4 per block (t < 512) ----
    if (t < 512) {
        const float4* px = (const float4*)x + (size_t)g * 1024 + t * 2;
        float4 a = px[0], b = px[1];
        uint4 o;
        o.x = f2bf(a.x) | (f2bf(a.y) << 16);
        o.y = f2bf(a.z) | (f2bf(a.w) << 16);
        o.z = f2bf(b.x) | (f2bf(b.y) << 16);
        o.w = f2bf(b.z) | (f2bf(b.w) << 16);
        xb[(size_t)g * 512 + t] = o;
    }

    int   rr[CHK / 1024];
    int   cc[CHK / 1024];
    float vv[CHK / 1024];
    for (int i = t; i < 4 * NBK; i += 1024) ((int*)hist4)[i] = 0;
    __syncthreads();
#pragma unroll
    for (int k = 0; k < CHK / 1024; ++k) {
        int i = s + t + k * 1024;
        if (i < e) {
            rr[k] = rows[i];
            cc[k] = cols[i];
            vv[k] = vals[i];
            atomicAdd(&hist4[rep][rr[k] >> 4], 1);
        } else rr[k] = -1;
    }
    __syncthreads();
    // bin totals -> binStart (as temp), then group scan
    if (t < NBK)
        binStart[t] = hist4[0][t] + hist4[1][t] + hist4[2][t] + hist4[3][t];
    __syncthreads();
    if (t < 64) {
        int gs = 0;
#pragma unroll
        for (int k = 0; k < 8; ++k) gs += binStart[t * 8 + k];
        gbase[t] = gs;
    }
    __syncthreads();
    if (t == 0) {
        int acc = 0;
        for (int i = 0; i < 64; ++i) { int c = gbase[i]; gbase[i] = acc; acc += c; }
    }
    __syncthreads();
    int off = 0;
    if (t < NBK) {
        off = gbase[t >> 3];
        for (int k = (t & ~7); k < t; ++k) off += binStart[k];   // totals of same-group bins
    }
    __syncthreads();                               // all total-reads done
    if (t < NBK) {
        binStart[t] = off;
        binStartT[(size_t)t * NG + g] = off;       // publish local bin start
        // per-replica cursor bases (disjoint sub-ranges within the bin)
        int run = off;
#pragma unroll
        for (int r = 0; r < 4; ++r) {
            int c = hist4[r][t];
            hist4[r][t] = run;
            run += c;
        }
    }
    __syncthreads();
#pragma unroll
    for (int k = 0; k < CHK / 1024; ++k) {
        if (rr[k] >= 0) {
            int pos = atomicAdd(&hist4[rep][rr[k] >> 4], 1);
            stage[pos] = make_int2((rr[k] << 13) | cc[k], __float_as_int(vv[k]));
        }
    }
    __syncthreads();
    // chunk-contiguous coalesced writeout (sorted by bucket within the chunk)
#pragma unroll
    for (int k = 0; k < CHK / 1024; ++k) {
        int i = t + k * 1024;
        if (i < cnt) pairs[s + i] = stage[i];
    }
}

// ---------- K2: per-bucket run-gather + LDS sort + spmm --------------------
// 1024 threads = 16 waves = 16 rows. Run table + sort verbatim R13. Gather:
// quarter-wave per entry (16 lanes x uint4), 16 entries/iter; packed FMA with
// unmasked-high bf16 pairs. Verbatim R15.
__global__ void __launch_bounds__(1024) bucketspmm_kernel(const int2* __restrict__ pairs,
                                                          const int* __restrict__ binStartT,
                                                          int nnz,
                                                          const unsigned short* __restrict__ xb,
                                                          float* __restrict__ out) {
    __shared__ int2 sorted[CAP];                   // 40 KB
    __shared__ int runPrefix[NG + 1];              // exclusive entry-prefix per run
    __shared__ int runAddr[NG];                    // global pairs index of run start
    __shared__ int gb16[16];
    __shared__ int h16w[16 * 16];                  // [wave][bin]
    __shared__ int h16tot[16];
    __shared__ int rs[17];
    int t = threadIdx.x;
    int bkt = blockIdx.x;
    int wave = t >> 6, lane = t & 63;

    // ---- run table: length + address per chunk ----
    if (t < NG) {
        int g = t;
        int st = binStartT[(size_t)bkt * NG + g];
        int en;
        if (bkt == NBK - 1) en = min(CHK, nnz - g * CHK);
        else                en = binStartT[(size_t)(bkt + 1) * NG + g];
        runAddr[g] = g * CHK + st;
        runPrefix[g] = en - st;                    // temporarily: run length
    }
    if (t < 256) h16w[t] = 0;
    __syncthreads();
    if (t < 16) {
        int gs = 0;
#pragma unroll
        for (int k = 0; k < 16; ++k) gs += runPrefix[t * 16 + k];
        gb16[t] = gs;
    }
    __syncthreads();
    if (t == 0) {
        int acc = 0;
        for (int i = 0; i < 16; ++i) { int c = gb16[i]; gb16[i] = acc; acc += c; }
    }
    __syncthreads();
    int myoff = 0, mylen = 0;
    if (t < NG) {
        mylen = runPrefix[t];
        myoff = gb16[t >> 4];
        for (int k = (t & ~15); k < t; ++k) myoff += runPrefix[k];
    }
    __syncthreads();
    if (t < NG) runPrefix[t] = myoff;              // now: exclusive prefix
    if (t == NG - 1) runPrefix[NG] = myoff + mylen;
    __syncthreads();

    int n = runPrefix[NG];
    int nc = min(n, CAP);

    // ---- staged load via run binary search + per-wave 16-bin hist ----
    int2 buf[5];                                   // CAP = 5 * 1024
#pragma unroll
    for (int k = 0; k < 5; ++k) {
        int i = t + 1024 * k;
        if (i < nc) {
            int lo = 0, hi = NG - 1;
#pragma unroll
            for (int st8 = 0; st8 < 8; ++st8) {
                int mid = (lo + hi + 1) >> 1;
                if (runPrefix[mid] <= i) lo = mid; else hi = mid - 1;
            }
            int2 en = pairs[runAddr[lo] + (i - runPrefix[lo])];
            buf[k] = en;
            atomicAdd(&h16w[wave * 16 + ((en.x >> 13) & 15)], 1);
        }
    }
    __syncthreads();
    if (t < 16) {                                  // bin = t: exclusive over waves
        int acc = 0;
#pragma unroll
        for (int w = 0; w < 16; ++w) {
            int c = h16w[w * 16 + t];
            h16w[w * 16 + t] = acc;
            acc += c;
        }
        h16tot[t] = acc;
    }
    __syncthreads();
    if (t == 0) {
        int acc = 0;
#pragma unroll
        for (int j = 0; j < 16; ++j) { rs[j] = acc; acc += h16tot[j]; }
        rs[16] = acc;
    }
    __syncthreads();
    if (t < 256) {                                 // per-wave cursor = rs[bin] + wave prefix
        int w = t >> 4, b = t & 15;
        h16w[t] = rs[b] + h16w[w * 16 + b];
    }
    __syncthreads();
#pragma unroll
    for (int k = 0; k < 5; ++k) {
        int i = t + 1024 * k;
        if (i < nc) {
            int2 en = buf[k];
            int pos = atomicAdd(&h16w[wave * 16 + ((en.x >> 13) & 15)], 1);
            sorted[pos] = make_int2(en.x & 8191, en.y);
        }
    }
    __syncthreads();

    // ---- spmm: wave `wave` computes row (bkt*16 + wave) ----
    int g = lane >> 4, l16 = lane & 15;
    const unsigned short* xbl = xb + l16 * 8;
    int b0 = rs[wave], e0 = rs[wave + 1];
    v2f acc2[4];
#pragma unroll
    for (int k = 0; k < 4; ++k) acc2[k] = (v2f){0.f, 0.f};

    for (int i = b0; i < e0; i += 16) {
        int i0 = i + g, i1 = i0 + 4, i2 = i0 + 8, i3 = i0 + 12;
        int2 ea = (i0 < e0) ? sorted[i0] : make_int2(0, 0);
        int2 eb = (i1 < e0) ? sorted[i1] : make_int2(0, 0);
        int2 ec = (i2 < e0) ? sorted[i2] : make_int2(0, 0);
        int2 ed = (i3 < e0) ? sorted[i3] : make_int2(0, 0);
        float va = (i0 < e0) ? __int_as_float(ea.y) : 0.f;
        float vb = (i1 < e0) ? __int_as_float(eb.y) : 0.f;
        float vc = (i2 < e0) ? __int_as_float(ec.y) : 0.f;
        float vd = (i3 < e0) ? __int_as_float(ed.y) : 0.f;
        const uint4 qa = *(const uint4*)(xbl + (size_t)ea.x * B_COLS);
        const uint4 qb = *(const uint4*)(xbl + (size_t)eb.x * B_COLS);
        const uint4 qc = *(const uint4*)(xbl + (size_t)ec.x * B_COLS);
        const uint4 qd = *(const uint4*)(xbl + (size_t)ed.x * B_COLS);
        // packed FMA: pair = {low bf16 (exact shift), high bf16 (UNMASKED, rel err < 2^-8)}
        v2f pva = (v2f){va, va}, pvb = (v2f){vb, vb};
        v2f pvc = (v2f){vc, vc}, pvd = (v2f){vd, vd};
#pragma unroll
        for (int k = 0; k < 4; ++k) {
            unsigned int w = (&qa.x)[k];
            v2f xv = (v2f){__uint_as_float(w << 16), __uint_as_float(w)};
            acc2[k] = __builtin_elementwise_fma(pva, xv, acc2[k]);
        }
#pragma unroll
        for (int k = 0; k < 4; ++k) {
            unsigned int w = (&qb.x)[k];
            v2f xv = (v2f){__uint_as_float(w << 16), __uint_as_float(w)};
            acc2[k] = __builtin_elementwise_fma(pvb, xv, acc2[k]);
        }
#pragma unroll
        for (int k = 0; k < 4; ++k) {
            unsigned int w = (&qc.x)[k];
            v2f xv = (v2f){__uint_as_float(w << 16), __uint_as_float(w)};
            acc2[k] = __builtin_elementwise_fma(pvc, xv, acc2[k]);
        }
#pragma unroll
        for (int k = 0; k < 4; ++k) {
            unsigned int w = (&qd.x)[k];
            v2f xv = (v2f){__uint_as_float(w << 16), __uint_as_float(w)};
            acc2[k] = __builtin_elementwise_fma(pvd, xv, acc2[k]);
        }
    }
    // overflow tail (n > CAP): correct but never taken for this data
    for (int i = CAP; i < n; ++i) {
        int lo = 0, hi = NG - 1;
        for (int st8 = 0; st8 < 8; ++st8) {
            int mid = (lo + hi + 1) >> 1;
            if (runPrefix[mid] <= i) lo = mid; else hi = mid - 1;
        }
        int2 en = pairs[runAddr[lo] + (i - runPrefix[lo])];
        if (((en.x >> 13) & 15) == wave) {
            float v = (g == 0) ? __int_as_float(en.y) : 0.f;
            v2f pv = (v2f){v, v};
            const uint4 q = *(const uint4*)(xbl + (size_t)(en.x & 8191) * B_COLS);
#pragma unroll
            for (int k = 0; k < 4; ++k) {
                unsigned int w = (&q.x)[k];
                v2f xv = (v2f){__uint_as_float(w << 16), __uint_as_float(w)};
                acc2[k] = __builtin_elementwise_fma(pv, xv, acc2[k]);
            }
        }
    }
    float acc[8];
#pragma unroll
    for (int k = 0; k < 4; ++k) { acc[2 * k] = acc2[k].x; acc[2 * k + 1] = acc2[k].y; }
#pragma unroll
    for (int k = 0; k < 8; ++k) {
        acc[k] += __shfl_xor(acc[k], 16, 64);
        acc[k] += __shfl_xor(acc[k], 32, 64);
    }
    if (lane < 16) {
        float* op = out + ((size_t)(bkt * 16 + wave)) * B_COLS + l16 * 8;
        *(float4*)op       = make_float4(acc[0], acc[1], acc[2], acc[3]);
        *((float4*)op + 1) = make_float4(acc[4], acc[5], acc[6], acc[7]);
    }
}

// ---------- Fallback if workspace too small / unexpected shape -------------
__global__ void atomic_spmm_kernel(const int* __restrict__ rows, const int* __restrict__ cols,
                                   const float* __restrict__ vals, int nnz,
                                   const float* __restrict__ x, float* __restrict__ out) {
    long long tid = (long long)blockIdx.x * blockDim.x + threadIdx.x;
    int e = (int)(tid >> 5);
    int g = (int)(tid & 31);
    if (e < nnz) {
        int r = rows[e], c = cols[e];
        float v = vals[e];
        const float4 xv = *(const float4*)(x + (size_t)c * B_COLS + g * 4);
        float* o = out + (size_t)r * B_COLS + g * 4;
        atomicAdd(o + 0, v * xv.x);
        atomicAdd(o + 1, v * xv.y);
        atomicAdd(o + 2, v * xv.z);
        atomicAdd(o + 3, v * xv.w);
    }
}

extern "C" void kernel_launch(void* const* d_in, const int* in_sizes, int n_in,
                              void* d_out, int out_size, void* d_ws, size_t ws_size,
                              hipStream_t stream) {
    const int*   ids  = (const int*)d_in[0];
    const int    nnz  = in_sizes[0] / 2;
    const int*   rows = ids;
    const int*   cols = ids + nnz;
    const float* vals = (const float*)d_in[1];
    const float* x    = (const float*)d_in[2];
    float*       out  = (float*)d_out;

    // ws (ints): binStartT[NBK*NG] | pad-to-16B | xbf[1M bf16 = 512K ints] | pairs[nnz] int2
    size_t o_binStartT = 0;
    size_t o_xbf       = (o_binStartT + (size_t)NBK * NG + 3) & ~(size_t)3;   // 16B align
    size_t o_pairs     = o_xbf + (size_t)M_ROWS * B_COLS / 2;
    size_t need_bytes  = (o_pairs + (size_t)nnz * 2) * 4;
    int ngrid = (nnz + CHK - 1) / CHK;             // = NG for this data

    if (ws_size >= need_bytes && ngrid == NG) {
        int*            binStartT = (int*)d_ws + o_binStartT;
        unsigned short* xbf       = (unsigned short*)((int*)d_ws + o_xbf);
        int2*           pairs     = (int2*)((int*)d_ws + o_pairs);

        chunksort_kernel<<<NG, 1024, 0, stream>>>(rows, cols, vals, nnz,
                                                  x, (uint4*)xbf, binStartT, pairs);
        bucketspmm_kernel<<<NBK, 1024, 0, stream>>>(pairs, binStartT, nnz, xbf, out);
    } else {
        hipMemsetAsync(d_out, 0, (size_t)out_size * sizeof(float), stream);
        long long total = (long long)nnz * 32;
        atomic_spmm_kernel<<<(unsigned)((total + 255) / 256), 256, 0, stream>>>(rows, cols, vals, nnz, x, out);
    }
}